// Round 8
// baseline (510.918 us; speedup 1.0000x reference)
//
#include <hip/hip_runtime.h>

#define N 8192
#define DIN 512
#define DOUT 256
#define ALPHA 0.2f
#define NEG_INF -9.0e15f

typedef __attribute__((ext_vector_type(8))) short bf16x8;
typedef __attribute__((ext_vector_type(4))) float f32x4;
typedef __attribute__((ext_vector_type(4))) int   i32x4;

__device__ __forceinline__ unsigned f2bf_u(float f) {
    unsigned u = __builtin_bit_cast(unsigned, f);
    return (u + 0x7fffu + ((u >> 16) & 1u)) >> 16;   // RNE bf16
}
__device__ __forceinline__ unsigned pack2bf(float lo, float hi) {
    return f2bf_u(lo) | (f2bf_u(hi) << 16);
}
__device__ __forceinline__ float bf2f(ushort u) {
    return __builtin_bit_cast(float, (unsigned)u << 16);
}
union U4BF8 { uint4 u; bf16x8 v; };

__device__ __forceinline__ void async_copy16(const ushort* g, ushort* l) {
    __builtin_amdgcn_global_load_lds(
        (const __attribute__((address_space(1))) unsigned*)g,
        (__attribute__((address_space(3))) unsigned*)l, 16, 0, 0);
}

// Kernel 0: W fp32 [512][256] -> WB bf16 in MFMA-B layout ((k>>3)*256+c)*8+(k&7).
__global__ __launch_bounds__(256) void wb_kernel(const float* __restrict__ W,
                                                 ushort* __restrict__ WB) {
    const int g = blockIdx.x * 256 + threadIdx.x;   // 64*256 = 16384
    const int c = g & 255, k8 = g >> 8;
    const float* wp = W + (size_t)(k8 * 8) * DOUT + c;
    U4BF8 o;
    o.u.x = pack2bf(wp[0 * DOUT], wp[1 * DOUT]);
    o.u.y = pack2bf(wp[2 * DOUT], wp[3 * DOUT]);
    o.u.z = pack2bf(wp[4 * DOUT], wp[5 * DOUT]);
    o.u.w = pack2bf(wp[6 * DOUT], wp[7 * DOUT]);
    *(uint4*)(WB + (size_t)g * 8) = o.u;
}

// Kernel 1: h = X@W + b via MFMA, split-K across 4 waves (unchanged).
__global__ __launch_bounds__(256) void h_kernel(
        const float* __restrict__ X, const ushort* __restrict__ WB,
        const float* __restrict__ bvec, const float* __restrict__ a,
        ushort* __restrict__ hB, float* __restrict__ el, float* __restrict__ er)
{
    __shared__ float red[4][64][65];
    __shared__ float elr[2][4][16];
    const int t = threadIdx.x;
    const int w = t >> 6, l = t & 63, q = l >> 4, n = l & 15;
    const int i0 = blockIdx.x * 16;
    f32x4 acc[16];
    #pragma unroll
    for (int ct = 0; ct < 16; ++ct) acc[ct] = (f32x4){0.f, 0.f, 0.f, 0.f};
    const float* xp = X + (size_t)(i0 + n) * DIN + q * 8;

    #pragma unroll
    for (int ks = 0; ks < 4; ++ks) {
        const int k0 = w * 128 + ks * 32;
        const float4 x0 = *(const float4*)(xp + k0);
        const float4 x1 = *(const float4*)(xp + k0 + 4);
        U4BF8 pa;
        pa.u.x = pack2bf(x0.x, x0.y); pa.u.y = pack2bf(x0.z, x0.w);
        pa.u.z = pack2bf(x1.x, x1.y); pa.u.w = pack2bf(x1.z, x1.w);
        const ushort* wbp = WB + ((k0 >> 3) + q) * 2048 + n * 8;
        bf16x8 bfr[16];
        #pragma unroll
        for (int ct = 0; ct < 16; ++ct) bfr[ct] = *(const bf16x8*)(wbp + ct * 128);
        #pragma unroll
        for (int ct = 0; ct < 16; ++ct)
            acc[ct] = __builtin_amdgcn_mfma_f32_16x16x32_bf16(pa.v, bfr[ct], acc[ct], 0, 0, 0);
    }
    #pragma unroll
    for (int ct = 0; ct < 16; ++ct)
        #pragma unroll
        for (int r = 0; r < 4; ++r) red[w][l][ct * 4 + r] = acc[ct][r];
    __syncthreads();

    float pl[4] = {0.f, 0.f, 0.f, 0.f}, pr[4] = {0.f, 0.f, 0.f, 0.f};
    const int hbase = (blockIdx.x * 2 + (q >> 1)) * 2048 + n * 8 + (q & 1) * 4;
    #pragma unroll
    for (int c2 = 0; c2 < 4; ++c2) {
        const int ct = w * 4 + c2;
        const float bb = bvec[ct * 16 + n];
        const float al = a[ct * 16 + n];
        const float ar = a[DOUT + ct * 16 + n];
        float v[4];
        #pragma unroll
        for (int r = 0; r < 4; ++r) {
            v[r] = red[0][l][ct * 4 + r] + red[1][l][ct * 4 + r]
                 + red[2][l][ct * 4 + r] + red[3][l][ct * 4 + r] + bb;
            pl[r] += v[r] * al;
            pr[r] += v[r] * ar;
        }
        ushort4 hp;
        hp.x = (ushort)f2bf_u(v[0]); hp.y = (ushort)f2bf_u(v[1]);
        hp.z = (ushort)f2bf_u(v[2]); hp.w = (ushort)f2bf_u(v[3]);
        *(ushort4*)&hB[hbase + ct * 128] = hp;
    }
    #pragma unroll
    for (int r = 0; r < 4; ++r) {
        #pragma unroll
        for (int off = 1; off < 16; off <<= 1) {
            pl[r] += __shfl_xor(pl[r], off);
            pr[r] += __shfl_xor(pr[r], off);
        }
    }
    if (n == 0) {
        #pragma unroll
        for (int r = 0; r < 4; ++r) {
            elr[0][w][q * 4 + r] = pl[r];
            elr[1][w][q * 4 + r] = pr[r];
        }
    }
    __syncthreads();
    if (t < 16) {
        el[i0 + t] = elr[0][0][t] + elr[0][1][t] + elr[0][2][t] + elr[0][3][t];
        er[i0 + t] = elr[1][0][t] + elr[1][1][t] + elr[1][2][t] + elr[1][3][t];
    }
}

// Kernel 2: attention partials. Block = 256 rows x 1024 j. grid 256 =
// 32 rb x 8 jq (jq in low bits -> XCD-local hB slice, L2-resident).
// Wave w owns 32 rows (two 16-row A-frags sharing every B ds_read -> LDS
// traffic per unit work halved). 8 steps of 128 j; adj register-double-
// buffered; hB tiles double-buffered in LDS via global_load_lds.
__global__ __launch_bounds__(512, 2) void attn_kernel(
        const int* __restrict__ adj, const float* __restrict__ el,
        const float* __restrict__ er, const float* __restrict__ ab,
        const ushort* __restrict__ hB, ushort* __restrict__ pout,
        float* __restrict__ plsum)
{
    __shared__ ushort stage[2][32768];   // 2 x 64 KB
    __shared__ float ers[1024];          // 4 KB
    const int t = threadIdx.x;
    const int w = t >> 6, l = t & 63, q = l >> 4, n = l & 15;
    const int rb = blockIdx.x >> 3, jq = blockIdx.x & 7;
    const int j0 = jq * 1024;
    const int rowA = rb * 256 + w * 32 + n;      // rg0; rg1 = rowA + 16
    const float elmA = el[rowA] + ab[0];
    const float elmB = el[rowA + 16] + ab[0];
    const int* apA = adj + (size_t)rowA * N + j0 + q * 8;
    const int* apB = apA + (size_t)16 * N;

    f32x4 acc0[16], acc1[16];
    #pragma unroll
    for (int ct = 0; ct < 16; ++ct) {
        acc0[ct] = (f32x4){0.f, 0.f, 0.f, 0.f};
        acc1[ct] = (f32x4){0.f, 0.f, 0.f, 0.f};
    }
    float lsumA = 0.f, lsumB = 0.f;

    // prologue: er slice -> LDS; adj regs for step 0; hB step-0 tile -> stage[0]
    *(float2*)&ers[t * 2] = *(const float2*)&er[j0 + t * 2];
    i32x4 a[16];
    #pragma unroll
    for (int kg = 0; kg < 4; ++kg) {
        a[2 * kg]     = *(const i32x4*)(apA + kg * 32);
        a[2 * kg + 1] = *(const i32x4*)(apA + kg * 32 + 4);
        a[8 + 2 * kg] = *(const i32x4*)(apB + kg * 32);
        a[9 + 2 * kg] = *(const i32x4*)(apB + kg * 32 + 4);
    }
    {
        const ushort* g = hB + (size_t)j0 * 256 + t * 8;
        ushort* lb = &stage[0][t * 8];
        #pragma unroll
        for (int i = 0; i < 8; ++i) async_copy16(g + i * 4096, lb + i * 4096);
    }

    for (int s = 0; s < 8; ++s) {
        __syncthreads();                 // stage[s&1] staged; adj regs for s ready
        // 1. p/exp for both row-groups (consumes a[], freeing it)
        U4BF8 paA[4], paB[4];
        #pragma unroll
        for (int kg = 0; kg < 4; ++kg) {
            const float4 e0 = *(const float4*)&ers[s * 128 + kg * 32 + q * 8];
            const float4 e1 = *(const float4*)&ers[s * 128 + kg * 32 + q * 8 + 4];
            float v, p0, p1, p2, p3, p4, p5, p6, p7;
            i32x4 a0 = a[2 * kg], a1 = a[2 * kg + 1];
            v = elmA + e0.x; v = fmaxf(v, ALPHA * v); p0 = __expf(a0.x > 0 ? v : NEG_INF);
            v = elmA + e0.y; v = fmaxf(v, ALPHA * v); p1 = __expf(a0.y > 0 ? v : NEG_INF);
            v = elmA + e0.z; v = fmaxf(v, ALPHA * v); p2 = __expf(a0.z > 0 ? v : NEG_INF);
            v = elmA + e0.w; v = fmaxf(v, ALPHA * v); p3 = __expf(a0.w > 0 ? v : NEG_INF);
            v = elmA + e1.x; v = fmaxf(v, ALPHA * v); p4 = __expf(a1.x > 0 ? v : NEG_INF);
            v = elmA + e1.y; v = fmaxf(v, ALPHA * v); p5 = __expf(a1.y > 0 ? v : NEG_INF);
            v = elmA + e1.z; v = fmaxf(v, ALPHA * v); p6 = __expf(a1.z > 0 ? v : NEG_INF);
            v = elmA + e1.w; v = fmaxf(v, ALPHA * v); p7 = __expf(a1.w > 0 ? v : NEG_INF);
            lsumA += p0 + p1 + p2 + p3 + p4 + p5 + p6 + p7;
            paA[kg].u.x = pack2bf(p0, p1); paA[kg].u.y = pack2bf(p2, p3);
            paA[kg].u.z = pack2bf(p4, p5); paA[kg].u.w = pack2bf(p6, p7);
            a0 = a[8 + 2 * kg]; a1 = a[9 + 2 * kg];
            v = elmB + e0.x; v = fmaxf(v, ALPHA * v); p0 = __expf(a0.x > 0 ? v : NEG_INF);
            v = elmB + e0.y; v = fmaxf(v, ALPHA * v); p1 = __expf(a0.y > 0 ? v : NEG_INF);
            v = elmB + e0.z; v = fmaxf(v, ALPHA * v); p2 = __expf(a0.z > 0 ? v : NEG_INF);
            v = elmB + e0.w; v = fmaxf(v, ALPHA * v); p3 = __expf(a0.w > 0 ? v : NEG_INF);
            v = elmB + e1.x; v = fmaxf(v, ALPHA * v); p4 = __expf(a1.x > 0 ? v : NEG_INF);
            v = elmB + e1.y; v = fmaxf(v, ALPHA * v); p5 = __expf(a1.y > 0 ? v : NEG_INF);
            v = elmB + e1.z; v = fmaxf(v, ALPHA * v); p6 = __expf(a1.z > 0 ? v : NEG_INF);
            v = elmB + e1.w; v = fmaxf(v, ALPHA * v); p7 = __expf(a1.w > 0 ? v : NEG_INF);
            lsumB += p0 + p1 + p2 + p3 + p4 + p5 + p6 + p7;
            paB[kg].u.x = pack2bf(p0, p1); paB[kg].u.y = pack2bf(p2, p3);
            paB[kg].u.z = pack2bf(p4, p5); paB[kg].u.w = pack2bf(p6, p7);
        }
        // 2. issue step s+1 traffic (adj regs now free)
        if (s < 7) {
            const int off = (s + 1) * 128;
            #pragma unroll
            for (int kg = 0; kg < 4; ++kg) {
                a[2 * kg]     = *(const i32x4*)(apA + off + kg * 32);
                a[2 * kg + 1] = *(const i32x4*)(apA + off + kg * 32 + 4);
                a[8 + 2 * kg] = *(const i32x4*)(apB + off + kg * 32);
                a[9 + 2 * kg] = *(const i32x4*)(apB + off + kg * 32 + 4);
            }
            const ushort* g = hB + (size_t)(j0 + off) * 256 + t * 8;
            ushort* lb = &stage[(s + 1) & 1][t * 8];
            #pragma unroll
            for (int i = 0; i < 8; ++i) async_copy16(g + i * 4096, lb + i * 4096);
        }
        // 3. MFMA: every B-fragment read feeds BOTH row-groups
        #pragma unroll
        for (int kg = 0; kg < 4; ++kg) {
            const ushort* sb = &stage[s & 1][(kg * 4 + q) * 2048 + n * 8];
            #pragma unroll
            for (int ct = 0; ct < 16; ++ct) {
                const bf16x8 bf = *(const bf16x8*)(sb + ct * 128);
                acc0[ct] = __builtin_amdgcn_mfma_f32_16x16x32_bf16(paA[kg].v, bf, acc0[ct], 0, 0, 0);
                acc1[ct] = __builtin_amdgcn_mfma_f32_16x16x32_bf16(paB[kg].v, bf, acc1[ct], 0, 0, 0);
            }
        }
    }

    // row sums: reduce across the 4 q-groups holding each row
    lsumA += __shfl_xor(lsumA, 16);
    lsumA += __shfl_xor(lsumA, 32);
    lsumB += __shfl_xor(lsumB, 16);
    lsumB += __shfl_xor(lsumB, 32);
    if (l < 16) {
        plsum[(size_t)jq * N + rowA] = lsumA;
        plsum[(size_t)jq * N + rowA + 16] = lsumB;
    }

    // unnormalized bf16 partials: rows rb*256 + w*32 (+16 for rg1) + q*4+r
    ushort* pb0 = pout + ((size_t)jq * N + rb * 256 + w * 32 + q * 4) * 256 + n;
    ushort* pb1 = pb0 + 16 * 256;
    #pragma unroll
    for (int ct = 0; ct < 16; ++ct)
        #pragma unroll
        for (int r = 0; r < 4; ++r) {
            __builtin_nontemporal_store((ushort)f2bf_u(acc0[ct][r]),
                                        pb0 + (size_t)r * 256 + ct * 16);
            __builtin_nontemporal_store((ushort)f2bf_u(acc1[ct][r]),
                                        pb1 + (size_t)r * 256 + ct * 16);
        }
}

// Kernel 3: combine 8 bf16 j-slice partials + normalize. grid 2048 x 256.
__global__ __launch_bounds__(256) void combine_kernel(
        const ushort* __restrict__ pout, const float* __restrict__ plsum,
        float* __restrict__ out)
{
    const int t = threadIdx.x;
    const int row = blockIdx.x * 4 + (t >> 6);
    const int c = (t & 63) * 4;
    const size_t idx = (size_t)row * 256 + c;
    const size_t qs = (size_t)N * 256;
    float4 o = {0.f, 0.f, 0.f, 0.f};
    float ls = 0.f;
    #pragma unroll
    for (int p = 0; p < 8; ++p) {
        const ushort4 v = *(const ushort4*)&pout[idx + p * qs];
        o.x += bf2f(v.x); o.y += bf2f(v.y); o.z += bf2f(v.z); o.w += bf2f(v.w);
        ls += plsum[p * N + row];
    }
    const float li = 1.0f / ls;
    o.x *= li; o.y *= li; o.z *= li; o.w *= li;
    *(float4*)&out[idx] = o;
}

extern "C" void kernel_launch(void* const* d_in, const int* in_sizes, int n_in,
                              void* d_out, int out_size, void* d_ws, size_t ws_size,
                              hipStream_t stream) {
    const int*   adj = (const int*)  d_in[0];
    const float* X   = (const float*)d_in[1];
    const float* W   = (const float*)d_in[2];
    const float* b   = (const float*)d_in[3];
    const float* a   = (const float*)d_in[4];
    const float* ab  = (const float*)d_in[5];
    float* out = (float*)d_out;

    ushort* hB    = (ushort*)d_ws;                        // 4 MB
    ushort* WB    = hB + (size_t)N * DOUT;                // 256 KB
    float*  el    = (float*)(WB + (size_t)DIN * DOUT);    // 32 KB
    float*  er    = el + N;                               // 32 KB
    float*  plsum = er + N;                               // 8*N fp32 = 256 KB
    ushort* pout  = (ushort*)(plsum + 8 * N);             // 8*N*256 bf16 = 32 MB

    wb_kernel<<<dim3(64), dim3(256), 0, stream>>>(W, WB);
    h_kernel<<<dim3(N / 16), dim3(256), 0, stream>>>(X, WB, b, a, hB, el, er);
    attn_kernel<<<dim3(256), dim3(512), 0, stream>>>(adj, el, er, ab, hB, pout, plsum);
    combine_kernel<<<dim3(N / 4), dim3(256), 0, stream>>>(pout, plsum, out);
}

// Round 9
// 447.961 us; speedup vs baseline: 1.1405x; 1.1405x over previous
//
#include <hip/hip_runtime.h>

#define N 8192
#define DIN 512
#define DOUT 256
#define ALPHA 0.2f
#define NEG_INF -9.0e15f

typedef __attribute__((ext_vector_type(8))) short bf16x8;
typedef __attribute__((ext_vector_type(4))) float f32x4;
typedef __attribute__((ext_vector_type(4))) int   i32x4;

__device__ __forceinline__ unsigned f2bf_u(float f) {
    unsigned u = __builtin_bit_cast(unsigned, f);
    return (u + 0x7fffu + ((u >> 16) & 1u)) >> 16;   // RNE bf16
}
__device__ __forceinline__ unsigned pack2bf(float lo, float hi) {
    return f2bf_u(lo) | (f2bf_u(hi) << 16);
}
__device__ __forceinline__ float bf2f_lo(unsigned u) {
    return __builtin_bit_cast(float, u << 16);
}
__device__ __forceinline__ float bf2f_hi(unsigned u) {
    return __builtin_bit_cast(float, u & 0xffff0000u);
}
union U4BF8 { uint4 u; bf16x8 v; };

__device__ __forceinline__ void async_copy16(const ushort* g, ushort* l) {
    __builtin_amdgcn_global_load_lds(
        (const __attribute__((address_space(1))) unsigned*)g,
        (__attribute__((address_space(3))) unsigned*)l, 16, 0, 0);
}

// Kernel 0: W fp32 [512][256] -> WB bf16 in MFMA-B layout ((k>>3)*256+c)*8+(k&7).
__global__ __launch_bounds__(256) void wb_kernel(const float* __restrict__ W,
                                                 ushort* __restrict__ WB) {
    const int g = blockIdx.x * 256 + threadIdx.x;   // 64*256 = 16384
    const int c = g & 255, k8 = g >> 8;
    const float* wp = W + (size_t)(k8 * 8) * DOUT + c;
    U4BF8 o;
    o.u.x = pack2bf(wp[0 * DOUT], wp[1 * DOUT]);
    o.u.y = pack2bf(wp[2 * DOUT], wp[3 * DOUT]);
    o.u.z = pack2bf(wp[4 * DOUT], wp[5 * DOUT]);
    o.u.w = pack2bf(wp[6 * DOUT], wp[7 * DOUT]);
    *(uint4*)(WB + (size_t)g * 8) = o.u;
}

// Kernel P: adj int32 -> bitmask, 1 bit/edge, 1024 B/row. Byte p = q*4 + kg
// of each 16-byte/128-j group holds j-chunk kg*4+q, so attn lane q reads its
// 4 kg-bytes as one dword at byte offset q*4. (R7-proven layout.)
__global__ __launch_bounds__(256) void pack_kernel(const int* __restrict__ adj,
                                                   unsigned char* __restrict__ bits) {
    const int t = threadIdx.x;
    const int r = blockIdx.x * 16 + (t >> 4);
    const int c = t & 15;
    const int* ap = adj + (size_t)r * N + c * 8;
    unsigned char* bp = bits + (size_t)r * (N / 8) + (c & 3) * 4 + (c >> 2);
    for (int s = 0; s < 64; ++s) {
        const i32x4 a0 = *(const i32x4*)(ap + s * 128);
        const i32x4 a1 = *(const i32x4*)(ap + s * 128 + 4);
        unsigned b = (a0.x > 0 ? 1u : 0u)  | (a0.y > 0 ? 2u : 0u)
                   | (a0.z > 0 ? 4u : 0u)  | (a0.w > 0 ? 8u : 0u)
                   | (a1.x > 0 ? 16u : 0u) | (a1.y > 0 ? 32u : 0u)
                   | (a1.z > 0 ? 64u : 0u) | (a1.w > 0 ? 128u : 0u);
        bp[s * 16] = (unsigned char)b;
    }
}

// Kernel 1: h = X@W + b via MFMA, split-K across 4 waves (unchanged).
__global__ __launch_bounds__(256) void h_kernel(
        const float* __restrict__ X, const ushort* __restrict__ WB,
        const float* __restrict__ bvec, const float* __restrict__ a,
        ushort* __restrict__ hB, float* __restrict__ el, float* __restrict__ er)
{
    __shared__ float red[4][64][65];
    __shared__ float elr[2][4][16];
    const int t = threadIdx.x;
    const int w = t >> 6, l = t & 63, q = l >> 4, n = l & 15;
    const int i0 = blockIdx.x * 16;
    f32x4 acc[16];
    #pragma unroll
    for (int ct = 0; ct < 16; ++ct) acc[ct] = (f32x4){0.f, 0.f, 0.f, 0.f};
    const float* xp = X + (size_t)(i0 + n) * DIN + q * 8;

    #pragma unroll
    for (int ks = 0; ks < 4; ++ks) {
        const int k0 = w * 128 + ks * 32;
        const float4 x0 = *(const float4*)(xp + k0);
        const float4 x1 = *(const float4*)(xp + k0 + 4);
        U4BF8 pa;
        pa.u.x = pack2bf(x0.x, x0.y); pa.u.y = pack2bf(x0.z, x0.w);
        pa.u.z = pack2bf(x1.x, x1.y); pa.u.w = pack2bf(x1.z, x1.w);
        const ushort* wbp = WB + ((k0 >> 3) + q) * 2048 + n * 8;
        bf16x8 bfr[16];
        #pragma unroll
        for (int ct = 0; ct < 16; ++ct) bfr[ct] = *(const bf16x8*)(wbp + ct * 128);
        #pragma unroll
        for (int ct = 0; ct < 16; ++ct)
            acc[ct] = __builtin_amdgcn_mfma_f32_16x16x32_bf16(pa.v, bfr[ct], acc[ct], 0, 0, 0);
    }
    #pragma unroll
    for (int ct = 0; ct < 16; ++ct)
        #pragma unroll
        for (int r = 0; r < 4; ++r) red[w][l][ct * 4 + r] = acc[ct][r];
    __syncthreads();

    float pl[4] = {0.f, 0.f, 0.f, 0.f}, pr[4] = {0.f, 0.f, 0.f, 0.f};
    const int hbase = (blockIdx.x * 2 + (q >> 1)) * 2048 + n * 8 + (q & 1) * 4;
    #pragma unroll
    for (int c2 = 0; c2 < 4; ++c2) {
        const int ct = w * 4 + c2;
        const float bb = bvec[ct * 16 + n];
        const float al = a[ct * 16 + n];
        const float ar = a[DOUT + ct * 16 + n];
        float v[4];
        #pragma unroll
        for (int r = 0; r < 4; ++r) {
            v[r] = red[0][l][ct * 4 + r] + red[1][l][ct * 4 + r]
                 + red[2][l][ct * 4 + r] + red[3][l][ct * 4 + r] + bb;
            pl[r] += v[r] * al;
            pr[r] += v[r] * ar;
        }
        ushort4 hp;
        hp.x = (ushort)f2bf_u(v[0]); hp.y = (ushort)f2bf_u(v[1]);
        hp.z = (ushort)f2bf_u(v[2]); hp.w = (ushort)f2bf_u(v[3]);
        *(ushort4*)&hB[hbase + ct * 128] = hp;
    }
    #pragma unroll
    for (int r = 0; r < 4; ++r) {
        #pragma unroll
        for (int off = 1; off < 16; off <<= 1) {
            pl[r] += __shfl_xor(pl[r], off);
            pr[r] += __shfl_xor(pr[r], off);
        }
    }
    if (n == 0) {
        #pragma unroll
        for (int r = 0; r < 4; ++r) {
            elr[0][w][q * 4 + r] = pl[r];
            elr[1][w][q * 4 + r] = pr[r];
        }
    }
    __syncthreads();
    if (t < 16) {
        el[i0 + t] = elr[0][0][t] + elr[0][1][t] + elr[0][2][t] + elr[0][3][t];
        er[i0 + t] = elr[1][0][t] + elr[1][1][t] + elr[1][2][t] + elr[1][3][t];
    }
}

// Kernel 2: attention partials from bitmask. Block = 256 rows x 1024 j.
// grid 256 = 32 rb x 8 jq (jq low bits -> XCD-local hB slice). Wave w owns
// 32 rows: two 16-row A-frags share every B ds_read (LDS traffic/work
// halved vs 16-row). 8 steps x 128 j; hB double-buffered via
// global_load_lds; 1 mask dword per row-group per step. No spills:
// ~60 VGPR + 128 AGPR. pout written lane-contiguous (128 B/lane).
__global__ __launch_bounds__(512, 1) void attn_kernel(
        const unsigned char* __restrict__ bits, const float* __restrict__ el,
        const float* __restrict__ er, const float* __restrict__ ab,
        const ushort* __restrict__ hB, ushort* __restrict__ pout,
        float* __restrict__ plsum)
{
    __shared__ ushort stage[2][32768];   // 2 x 64 KB
    __shared__ float ers[1024];          // 4 KB
    const int t = threadIdx.x;
    const int w = t >> 6, l = t & 63, q = l >> 4, n = l & 15;
    const int rb = blockIdx.x >> 3, jq = blockIdx.x & 7;
    const int j0 = jq * 1024;
    const int rowA = rb * 256 + w * 32 + n;      // rg0; rg1 = rowA + 16
    const float elmA = el[rowA] + ab[0];
    const float elmB = el[rowA + 16] + ab[0];
    const uint* mpA = (const uint*)(bits + (size_t)rowA * (N / 8) + jq * 128) + q;
    const uint* mpB = (const uint*)(bits + (size_t)(rowA + 16) * (N / 8) + jq * 128) + q;

    f32x4 acc0[16], acc1[16];
    #pragma unroll
    for (int ct = 0; ct < 16; ++ct) {
        acc0[ct] = (f32x4){0.f, 0.f, 0.f, 0.f};
        acc1[ct] = (f32x4){0.f, 0.f, 0.f, 0.f};
    }
    float lsumA = 0.f, lsumB = 0.f;

    // prologue: er slice -> LDS; masks for step 0; hB step-0 tile -> stage[0]
    *(float2*)&ers[t * 2] = *(const float2*)&er[j0 + t * 2];
    uint mA = mpA[0], mB = mpB[0];
    {
        const ushort* g = hB + (size_t)j0 * 256 + t * 8;
        ushort* lb = &stage[0][t * 8];
        #pragma unroll
        for (int i = 0; i < 8; ++i) async_copy16(g + i * 4096, lb + i * 4096);
    }

    for (int s = 0; s < 8; ++s) {
        __syncthreads();                 // stage[s&1] staged; masks for s held
        const uint mmA = mA, mmB = mB;
        if (s < 7) {                     // issue step s+1 traffic first
            mA = mpA[(s + 1) * 4];
            mB = mpB[(s + 1) * 4];
            const ushort* g = hB + (size_t)(j0 + (s + 1) * 128) * 256 + t * 8;
            ushort* lb = &stage[(s + 1) & 1][t * 8];
            #pragma unroll
            for (int i = 0; i < 8; ++i) async_copy16(g + i * 4096, lb + i * 4096);
        }
        // A-fragments for both row-groups: 4 kg x 8 j per lane
        U4BF8 paA[4], paB[4];
        #pragma unroll
        for (int kg = 0; kg < 4; ++kg) {
            const uint bkA = (mmA >> (kg * 8)) & 0xffu;
            const uint bkB = (mmB >> (kg * 8)) & 0xffu;
            const float4 e0 = *(const float4*)&ers[s * 128 + kg * 32 + q * 8];
            const float4 e1 = *(const float4*)&ers[s * 128 + kg * 32 + q * 8 + 4];
            float v, p0, p1, p2, p3, p4, p5, p6, p7;
            v = elmA + e0.x; v = fmaxf(v, ALPHA * v); p0 = __expf(bkA & 1u   ? v : NEG_INF);
            v = elmA + e0.y; v = fmaxf(v, ALPHA * v); p1 = __expf(bkA & 2u   ? v : NEG_INF);
            v = elmA + e0.z; v = fmaxf(v, ALPHA * v); p2 = __expf(bkA & 4u   ? v : NEG_INF);
            v = elmA + e0.w; v = fmaxf(v, ALPHA * v); p3 = __expf(bkA & 8u   ? v : NEG_INF);
            v = elmA + e1.x; v = fmaxf(v, ALPHA * v); p4 = __expf(bkA & 16u  ? v : NEG_INF);
            v = elmA + e1.y; v = fmaxf(v, ALPHA * v); p5 = __expf(bkA & 32u  ? v : NEG_INF);
            v = elmA + e1.z; v = fmaxf(v, ALPHA * v); p6 = __expf(bkA & 64u  ? v : NEG_INF);
            v = elmA + e1.w; v = fmaxf(v, ALPHA * v); p7 = __expf(bkA & 128u ? v : NEG_INF);
            lsumA += p0 + p1 + p2 + p3 + p4 + p5 + p6 + p7;
            paA[kg].u.x = pack2bf(p0, p1); paA[kg].u.y = pack2bf(p2, p3);
            paA[kg].u.z = pack2bf(p4, p5); paA[kg].u.w = pack2bf(p6, p7);
            v = elmB + e0.x; v = fmaxf(v, ALPHA * v); p0 = __expf(bkB & 1u   ? v : NEG_INF);
            v = elmB + e0.y; v = fmaxf(v, ALPHA * v); p1 = __expf(bkB & 2u   ? v : NEG_INF);
            v = elmB + e0.z; v = fmaxf(v, ALPHA * v); p2 = __expf(bkB & 4u   ? v : NEG_INF);
            v = elmB + e0.w; v = fmaxf(v, ALPHA * v); p3 = __expf(bkB & 8u   ? v : NEG_INF);
            v = elmB + e1.x; v = fmaxf(v, ALPHA * v); p4 = __expf(bkB & 16u  ? v : NEG_INF);
            v = elmB + e1.y; v = fmaxf(v, ALPHA * v); p5 = __expf(bkB & 32u  ? v : NEG_INF);
            v = elmB + e1.z; v = fmaxf(v, ALPHA * v); p6 = __expf(bkB & 64u  ? v : NEG_INF);
            v = elmB + e1.w; v = fmaxf(v, ALPHA * v); p7 = __expf(bkB & 128u ? v : NEG_INF);
            lsumB += p0 + p1 + p2 + p3 + p4 + p5 + p6 + p7;
            paB[kg].u.x = pack2bf(p0, p1); paB[kg].u.y = pack2bf(p2, p3);
            paB[kg].u.z = pack2bf(p4, p5); paB[kg].u.w = pack2bf(p6, p7);
        }
        // MFMA: every B-fragment ds_read feeds BOTH row-groups
        #pragma unroll
        for (int kg = 0; kg < 4; ++kg) {
            const ushort* sb = &stage[s & 1][(kg * 4 + q) * 2048 + n * 8];
            #pragma unroll
            for (int ct = 0; ct < 16; ++ct) {
                const bf16x8 bf = *(const bf16x8*)(sb + ct * 128);
                acc0[ct] = __builtin_amdgcn_mfma_f32_16x16x32_bf16(paA[kg].v, bf, acc0[ct], 0, 0, 0);
                acc1[ct] = __builtin_amdgcn_mfma_f32_16x16x32_bf16(paB[kg].v, bf, acc1[ct], 0, 0, 0);
            }
        }
    }

    // row sums: reduce across the 4 q-groups holding each row
    lsumA += __shfl_xor(lsumA, 16);
    lsumA += __shfl_xor(lsumA, 32);
    lsumB += __shfl_xor(lsumB, 16);
    lsumB += __shfl_xor(lsumB, 32);
    if (l < 16) {
        plsum[(size_t)jq * N + rowA] = lsumA;
        plsum[(size_t)jq * N + rowA + 16] = lsumB;
    }

    // lane-contiguous bf16 partials: lane l writes 64 ushorts at offset l*64
    // within its 16-row group's 8 KB slab. Value (ct,r) -> ushort ct*4+r.
    ushort* pb0 = pout + (size_t)jq * N * 256
                + ((size_t)rb * 256 + w * 32) * 256 + l * 64;
    ushort* pb1 = pb0 + 16 * 256;
    #pragma unroll
    for (int c2 = 0; c2 < 8; ++c2) {
        uint4 o0, o1;
        o0.x = pack2bf(acc0[2 * c2][0],     acc0[2 * c2][1]);
        o0.y = pack2bf(acc0[2 * c2][2],     acc0[2 * c2][3]);
        o0.z = pack2bf(acc0[2 * c2 + 1][0], acc0[2 * c2 + 1][1]);
        o0.w = pack2bf(acc0[2 * c2 + 1][2], acc0[2 * c2 + 1][3]);
        *(uint4*)(pb0 + c2 * 8) = o0;
        o1.x = pack2bf(acc1[2 * c2][0],     acc1[2 * c2][1]);
        o1.y = pack2bf(acc1[2 * c2][2],     acc1[2 * c2][3]);
        o1.z = pack2bf(acc1[2 * c2 + 1][0], acc1[2 * c2 + 1][1]);
        o1.w = pack2bf(acc1[2 * c2 + 1][2], acc1[2 * c2 + 1][3]);
        *(uint4*)(pb1 + c2 * 8) = o1;
    }
}

// Kernel 3: combine 8 lane-contiguous bf16 partial slabs + normalize.
// grid 512 blocks (one 16-row group each) x 256 thr; thread t covers
// lane qn = t>>2, ct-quarter ct4 = t&3 -> 16 values (4 ct x 4 r).
__global__ __launch_bounds__(256) void combine_kernel(
        const ushort* __restrict__ pout, const float* __restrict__ plsum,
        float* __restrict__ out)
{
    __shared__ float linv[16];
    const int t = threadIdx.x;
    const int rg = blockIdx.x;
    if (t < 16) {
        float s = 0.f;
        #pragma unroll
        for (int p = 0; p < 8; ++p) s += plsum[p * N + rg * 16 + t];
        linv[t] = 1.0f / s;
    }
    __syncthreads();

    const size_t qs = (size_t)N * 256;
    const size_t base = (size_t)rg * 4096 + t * 16;
    float v[16];
    #pragma unroll
    for (int i = 0; i < 16; ++i) v[i] = 0.f;
    #pragma unroll
    for (int p = 0; p < 8; ++p) {
        const uint4 u0 = *(const uint4*)&pout[p * qs + base];
        const uint4 u1 = *(const uint4*)&pout[p * qs + base + 8];
        v[0]  += bf2f_lo(u0.x); v[1]  += bf2f_hi(u0.x);
        v[2]  += bf2f_lo(u0.y); v[3]  += bf2f_hi(u0.y);
        v[4]  += bf2f_lo(u0.z); v[5]  += bf2f_hi(u0.z);
        v[6]  += bf2f_lo(u0.w); v[7]  += bf2f_hi(u0.w);
        v[8]  += bf2f_lo(u1.x); v[9]  += bf2f_hi(u1.x);
        v[10] += bf2f_lo(u1.y); v[11] += bf2f_hi(u1.y);
        v[12] += bf2f_lo(u1.z); v[13] += bf2f_hi(u1.z);
        v[14] += bf2f_lo(u1.w); v[15] += bf2f_hi(u1.w);
    }
    const int qn = t >> 2, ct4 = t & 3;
    const int q = qn >> 4, n = qn & 15;
    #pragma unroll
    for (int cl = 0; cl < 4; ++cl) {
        const int col = (ct4 * 4 + cl) * 16 + n;
        #pragma unroll
        for (int r = 0; r < 4; ++r) {
            const int row = rg * 16 + q * 4 + r;
            out[(size_t)row * 256 + col] = v[cl * 4 + r] * linv[q * 4 + r];
        }
    }
}

extern "C" void kernel_launch(void* const* d_in, const int* in_sizes, int n_in,
                              void* d_out, int out_size, void* d_ws, size_t ws_size,
                              hipStream_t stream) {
    const int*   adj = (const int*)  d_in[0];
    const float* X   = (const float*)d_in[1];
    const float* W   = (const float*)d_in[2];
    const float* b   = (const float*)d_in[3];
    const float* a   = (const float*)d_in[4];
    const float* ab  = (const float*)d_in[5];
    float* out = (float*)d_out;

    ushort* hB    = (ushort*)d_ws;                        // 4 MB
    ushort* WB    = hB + (size_t)N * DOUT;                // 256 KB
    float*  el    = (float*)(WB + (size_t)DIN * DOUT);    // 32 KB
    float*  er    = el + N;                               // 32 KB
    float*  plsum = er + N;                               // 8*N fp32 = 256 KB
    ushort* pout  = (ushort*)(plsum + 8 * N);             // 8*N*256 bf16 = 32 MB
    unsigned char* bits = (unsigned char*)(pout + (size_t)8 * N * DOUT); // 8 MB

    wb_kernel<<<dim3(64), dim3(256), 0, stream>>>(W, WB);
    pack_kernel<<<dim3(N / 16), dim3(256), 0, stream>>>(adj, bits);
    h_kernel<<<dim3(N / 16), dim3(256), 0, stream>>>(X, WB, b, a, hB, el, er);
    attn_kernel<<<dim3(256), dim3(512), 0, stream>>>(bits, el, er, ab, hB, pout, plsum);
    combine_kernel<<<dim3(N / 16), dim3(256), 0, stream>>>(pout, plsum, out);
}